// Round 8
// baseline (37.751 us; speedup 1.0000x reference)
//
#include <hip/hip_runtime.h>

// Barnes-Wall Lambda16 quantizer — rolled pass-1 with mod-2 residual tables
// (R5's math, R7's register-safe structure) + bit-exact pass-2.
//
// Pass 1 (surrogate, rolled over k): residual dd_j(k) depends only on
// c_j(k) mod 2 (rint commutes with integer shifts in reals; f32 deviations
// are harmless for RANKING — validated absmax 0.0 in R5/R6):
//   dd0[j] = xh - rint(xh)            (c even)
//   dd1[j] = (xh-.5) - rint(xh-.5)    (c odd)
// Per k: select via the odd-mask O(k) (16 cndmask, mask word s_loaded),
//   Dtil = sum d^2 + par * (1 - 2*max|d|)    ( = D_k/4 in reals )
// parity via bitmasks (R5/R6/R7-validated):
//   par = (popcount((P1&O)|(P0&~O)) + par2(k)) & 1.
// Keep stable top-3 (strict <, earlier k wins ties) — R7 insert verbatim.
//
// Pass 2: bit-exact numpy pipeline eval_k (R2..R7-verified) on the 3
// survivors; winner by lexicographic (D,k) == numpy first-min; emit eval.
//
// Bit-exactness invariants for pass-2 (absmax must be 0.0):
//  - fp contract OFF; fmaf only where exact or single-rounding-identical:
//    fmaf(c,-0.5,xh) == fl(xh-c/2) == fl(fl(x-c)*0.5); fmaf(2,f,c) exact;
//    Xp = fmaf(bit,+-2,X) exact (integers).
//  - rintf == round-half-to-even == np.round; dd = x2 - f exact.
//  - first-max: contiguous-pair tournament, left wins ties (>=).
//  - corr = f + sign(dd) == ceil(xc)+floor(xc)-fc (incl. exact halves).
//  - e = Xp - x directly (single rounding); D in numpy's n=16 pairwise
//    order: r[j]=sq[j]+sq[j+8]; D=((r0+r1)+(r2+r3))+((r4+r5)+(r6+r7)).
//  - parity (pass-2): float sum-tree of integer-valued f (exact), cvt, &1.
//
// Register discipline (R5/R6 post-mortem): ROLLED pass-1; persistent set =
// x[16]+dd0[16]+dd1[16]+P0,P1+top3(6) ~ 62 regs, well under the 128 cap
// from __launch_bounds__(256,4) (honored — R3; amdgpu_waves_per_eu is
// NOT — R6). Gate counter: WRITE_SIZE must stay ~18 MB (no scratch).

constexpr int G5[5][16] = {
    {1,1,1,1,0,1,0,1,1,0,0,1,0,0,0,0},
    {0,1,1,1,1,0,1,0,1,1,0,0,1,0,0,0},
    {0,0,1,1,1,1,0,1,0,1,1,0,0,1,0,0},
    {0,0,0,1,1,1,1,0,1,0,1,1,0,0,1,0},
    {1,1,1,1,1,1,1,1,1,1,1,1,1,1,1,1}};

struct Masks { int m[16]; };
constexpr Masks make_masks() {
  Masks mk{};
  for (int j = 0; j < 16; ++j) {
    int m = 0;
    for (int i = 0; i < 5; ++i) m |= G5[i][j] << (4 - i);
    mk.m[j] = m;
  }
  return mk;
}
constexpr Masks mk = make_masks();

// Packed per-candidate word: bits 0..15 = odd-mask O(k), bit 16 = par2(k).
struct KW { unsigned w[32]; };
constexpr KW make_kw() {
  KW t{};
  for (int k = 0; k < 32; ++k) {
    unsigned om = 0, p2 = 0;
    for (int j = 0; j < 16; ++j) {
      int c = 0;
      for (int i = 0; i < 5; ++i) c += ((k >> (4 - i)) & 1) * G5[i][j];
      om |= (unsigned)(c & 1) << j;
      p2 ^= (unsigned)((c >> 1) & 1);
    }
    t.w[k] = om | (p2 << 16);
  }
  return t;
}
constexpr KW kwt = make_kw();

__device__ __forceinline__ int parity16i(const float (&f)[16]) {
  // exact: all addends are small integers
  float s0 = ((f[0] + f[1]) + (f[2] + f[3])) + ((f[4] + f[5]) + (f[6] + f[7]));
  float s1 = ((f[8] + f[9]) + (f[10] + f[11])) + ((f[12] + f[13]) + (f[14] + f[15]));
  return ((int)(s0 + s1)) & 1;
}

// Exact numpy-pipeline evaluation of candidate kk (R2..R7-verified).
template <bool EMIT>
__device__ __forceinline__ float eval_k(int kk, const float (&x)[16],
                                        const float (&xh)[16], float a,
                                        float (&y)[16]) {
#pragma clang fp contract(off)
  float f[16], dd[16];
#pragma unroll
  for (int j = 0; j < 16; ++j) {
    float c = (float)__builtin_popcount(kk & mk.m[j]);
    float x2 = __builtin_fmaf(c, -0.5f, xh[j]);  // == fl(xh - c/2)
    float fj = __builtin_rintf(x2);
    f[j] = fj;
    dd[j] = x2 - fj;                             // exact
  }
  const int par = parity16i(f);

  // first-occurrence argmax of |dd| -> onehot (left wins ties)
  float tv[16];
  int ti[16];
#pragma unroll
  for (int j = 0; j < 16; ++j) { tv[j] = __builtin_fabsf(dd[j]); ti[j] = 1 << j; }
#pragma unroll
  for (int w = 8; w >= 1; w >>= 1) {
#pragma unroll
    for (int j = 0; j < w; ++j) {
      bool L = tv[2 * j] >= tv[2 * j + 1];
      tv[j] = L ? tv[2 * j] : tv[2 * j + 1];
      ti[j] = L ? ti[2 * j] : ti[2 * j + 1];
    }
  }
  const int ohm = par ? ti[0] : 0;   // patch mask (0 when parity even)

  float sq[16];
#pragma unroll
  for (int j = 0; j < 16; ++j) {
    float c  = (float)__builtin_popcount(kk & mk.m[j]);
    float X  = __builtin_fmaf(2.0f, f[j], c);          // exact int
    float s2 = __builtin_copysignf(2.0f, dd[j]);       // corr direction
    float bitf = (float)((ohm >> j) & 1);
    float Xp = __builtin_fmaf(bitf, s2, X);            // exact int
    float e  = Xp - x[j];                              // single rounding
    sq[j] = e * e;
    if (EMIT) y[j] = Xp * a;
  }
  float r0 = sq[0] + sq[8],  r1 = sq[1] + sq[9];
  float r2 = sq[2] + sq[10], r3 = sq[3] + sq[11];
  float r4 = sq[4] + sq[12], r5 = sq[5] + sq[13];
  float r6 = sq[6] + sq[14], r7 = sq[7] + sq[15];
  return ((r0 + r1) + (r2 + r3)) + ((r4 + r5) + (r6 + r7));
}

__global__ __launch_bounds__(256, 4) void bw_quant_kernel(
    const float* __restrict__ x_in,
    const float* __restrict__ C_rep,   // unused (constexpr codebook)
    const float* __restrict__ a_ptr,
    float* __restrict__ y_out,
    int n_rows)
{
#pragma clang fp contract(off)
  const int row = blockIdx.x * 256 + threadIdx.x;
  if (row >= n_rows) return;

  const float a = a_ptr[0];

  float x[16];
  {
    const float4* xr4 = reinterpret_cast<const float4*>(x_in + (size_t)row * 16);
#pragma unroll
    for (int q = 0; q < 4; ++q) {
      float4 v = xr4[q];
      x[q * 4 + 0] = v.x / a;
      x[q * 4 + 1] = v.y / a;
      x[q * 4 + 2] = v.z / a;
      x[q * 4 + 3] = v.w / a;
    }
  }

  // -------- mod-2 signed residual tables + parity masks (pass-1) ----------
  float dd0[16], dd1[16];
  int P0 = 0, P1 = 0;   // bit j = parity of rint(xh_j) / rint(xh_j - 0.5)
#pragma unroll
  for (int j = 0; j < 16; ++j) {
    float xh = x[j] * 0.5f;                 // exact
    float t0 = __builtin_rintf(xh);
    dd0[j] = xh - t0;
    float h  = xh - 0.5f;
    float t1 = __builtin_rintf(h);
    dd1[j] = h - t1;
    P0 |= ((int)t0 & 1) << j;
    P1 |= ((int)t1 & 1) << j;
  }

  // -------- pass 1: surrogate ranking (ROLLED), keep stable top-3 ---------
  float b1 = __builtin_inff(), b2 = b1, b3 = b1;
  int k1 = 0, k2 = 0, k3 = 0;

#pragma unroll 1
  for (int k = 0; k < 32; ++k) {
    const unsigned w = kwt.w[k];        // uniform -> 4B s_load
    const unsigned O = w & 0xFFFFu;
    const int p2 = (int)(w >> 16);

    float d[16];
#pragma unroll
    for (int j = 0; j < 16; ++j)
      d[j] = ((O >> j) & 1u) ? dd1[j] : dd0[j];   // scalar-cond cndmask

    // ssum = sum d^2 : 4 parallel fma chains (surrogate precision)
    float s0 = __builtin_fmaf(d[0], d[0], __builtin_fmaf(d[1], d[1],
               __builtin_fmaf(d[2], d[2], d[3] * d[3])));
    float s1 = __builtin_fmaf(d[4], d[4], __builtin_fmaf(d[5], d[5],
               __builtin_fmaf(d[6], d[6], d[7] * d[7])));
    float s2 = __builtin_fmaf(d[8], d[8], __builtin_fmaf(d[9], d[9],
               __builtin_fmaf(d[10], d[10], d[11] * d[11])));
    float s3 = __builtin_fmaf(d[12], d[12], __builtin_fmaf(d[13], d[13],
               __builtin_fmaf(d[14], d[14], d[15] * d[15])));
    float s = (s0 + s1) + (s2 + s3);

    // mx = max |d| via v_max3 triples (abs folds as VOP3 src modifiers)
    float t0 = __builtin_fmaxf(__builtin_fmaxf(__builtin_fabsf(d[0]),  __builtin_fabsf(d[1])),  __builtin_fabsf(d[2]));
    float t1 = __builtin_fmaxf(__builtin_fmaxf(__builtin_fabsf(d[3]),  __builtin_fabsf(d[4])),  __builtin_fabsf(d[5]));
    float t2 = __builtin_fmaxf(__builtin_fmaxf(__builtin_fabsf(d[6]),  __builtin_fabsf(d[7])),  __builtin_fabsf(d[8]));
    float t3 = __builtin_fmaxf(__builtin_fmaxf(__builtin_fabsf(d[9]),  __builtin_fabsf(d[10])), __builtin_fabsf(d[11]));
    float t4 = __builtin_fmaxf(__builtin_fmaxf(__builtin_fabsf(d[12]), __builtin_fabsf(d[13])), __builtin_fabsf(d[14]));
    float mx = __builtin_fmaxf(__builtin_fmaxf(__builtin_fmaxf(t0, t1), t2),
                               __builtin_fmaxf(__builtin_fmaxf(t3, t4), __builtin_fabsf(d[15])));

    // mask parity (R5/R6/R7-validated)
    unsigned sel = (O & (unsigned)P1) | (~O & (unsigned)P0);
    int cnt = __builtin_popcount(sel) + p2;
    float spen = s + __builtin_fmaf(-2.0f, mx, 1.0f);
    float dtil = (cnt & 1) ? spen : s;

    // stable top-3 insert (strict <: earlier k wins ties) — R7 verbatim
    bool lt1 = dtil < b1, lt2 = dtil < b2, lt3 = dtil < b3;
    float nb3 = lt3 ? (lt2 ? b2 : dtil) : b3;  int nk3 = lt3 ? (lt2 ? k2 : k) : k3;
    float nb2 = lt2 ? (lt1 ? b1 : dtil) : b2;  int nk2 = lt2 ? (lt1 ? k1 : k) : k2;
    b3 = nb3; k3 = nk3;
    b2 = nb2; k2 = nk2;
    b1 = lt1 ? dtil : b1;  k1 = lt1 ? k : k1;
  }

  // -------- pass 2: exact evaluation of the 3 survivors -------------------
  float xh[16];
#pragma unroll
  for (int j = 0; j < 16; ++j) xh[j] = x[j] * 0.5f;   // exact

  float ydummy[16];
  float D1 = eval_k<false>(k1, x, xh, a, ydummy);
  float D2 = eval_k<false>(k2, x, xh, a, ydummy);
  float D3 = eval_k<false>(k3, x, xh, a, ydummy);

  // lexicographic (D, k) == numpy first-min over the candidate set
  bool c2 = (D2 < D1) || (D2 == D1 && k2 < k1);
  float Db = c2 ? D2 : D1;
  int kb = c2 ? k2 : k1;
  bool c3 = (D3 < Db) || (D3 == Db && k3 < kb);
  kb = c3 ? k3 : kb;

  // -------- emit: exact re-eval of the winner -----------------------------
  float y[16];
  (void)eval_k<true>(kb, x, xh, a, y);

  float4* yr4 = reinterpret_cast<float4*>(y_out + (size_t)row * 16);
#pragma unroll
  for (int q = 0; q < 4; ++q) {
    float4 v;
    v.x = y[q * 4 + 0]; v.y = y[q * 4 + 1];
    v.z = y[q * 4 + 2]; v.w = y[q * 4 + 3];
    yr4[q] = v;
  }
}

extern "C" void kernel_launch(void* const* d_in, const int* in_sizes, int n_in,
                              void* d_out, int out_size, void* d_ws, size_t ws_size,
                              hipStream_t stream) {
  const float* x_in  = (const float*)d_in[0];
  const float* C_rep = (const float*)d_in[1];
  const float* a_ptr = (const float*)d_in[2];
  float* y_out = (float*)d_out;

  const int n_rows = in_sizes[0] / 16;
  const int block = 256;
  const int grid = (n_rows + block - 1) / block;
  bw_quant_kernel<<<grid, block, 0, stream>>>(x_in, C_rep, a_ptr, y_out, n_rows);
}